// Round 1
// baseline (157.589 us; speedup 1.0000x reference)
//
#include <hip/hip_runtime.h>

#define LN_EPS 1e-5f

// ---------------------------------------------------------------------------
// K1: tableA[p][m][j] = sum_i byte_emb[m][i] * pos_emb[p][i][j]
//   A: [256][512] row-major, B: [16][512][512] (row i, col j), C: [16][256][512]
// Classic 64x64 tile, BK=16, 256 threads, 4x4 per thread, fp32.
// ---------------------------------------------------------------------------
__global__ __launch_bounds__(256) void k1_gemm(
    const float* __restrict__ A,
    const float* __restrict__ B,
    float* __restrict__ C)
{
    const int p  = blockIdx.z;
    const int m0 = blockIdx.y * 64;
    const int n0 = blockIdx.x * 64;
    const float* __restrict__ Bp = B + (size_t)p * 512 * 512;
    float* __restrict__ Cp = C + (size_t)p * 256 * 512;

    __shared__ float As[16][64];
    __shared__ float Bs[16][68];   // +4 pad

    const int tid = threadIdx.x;
    const int am = tid >> 2, ak = (tid & 3) << 2;   // A tile: 64 rows x 16 k
    const int bk = tid >> 4, bn = (tid & 15) << 2;  // B tile: 16 k x 64 cols
    const int tx = tid & 15, ty = tid >> 4;

    float c[4][4] = {};

    for (int k0 = 0; k0 < 512; k0 += 16) {
        float4 av = *(const float4*)&A [(m0 + am) * 512 + k0 + ak];
        float4 bv = *(const float4*)&Bp[(size_t)(k0 + bk) * 512 + n0 + bn];
        __syncthreads();
        As[ak + 0][am] = av.x;
        As[ak + 1][am] = av.y;
        As[ak + 2][am] = av.z;
        As[ak + 3][am] = av.w;
        *(float4*)&Bs[bk][bn] = bv;
        __syncthreads();
        #pragma unroll
        for (int k = 0; k < 16; ++k) {
            float a0 = As[k][ty * 4 + 0], a1 = As[k][ty * 4 + 1];
            float a2 = As[k][ty * 4 + 2], a3 = As[k][ty * 4 + 3];
            float b0 = Bs[k][tx * 4 + 0], b1 = Bs[k][tx * 4 + 1];
            float b2 = Bs[k][tx * 4 + 2], b3 = Bs[k][tx * 4 + 3];
            c[0][0] += a0 * b0; c[0][1] += a0 * b1; c[0][2] += a0 * b2; c[0][3] += a0 * b3;
            c[1][0] += a1 * b0; c[1][1] += a1 * b1; c[1][2] += a1 * b2; c[1][3] += a1 * b3;
            c[2][0] += a2 * b0; c[2][1] += a2 * b1; c[2][2] += a2 * b2; c[2][3] += a2 * b3;
            c[3][0] += a3 * b0; c[3][1] += a3 * b1; c[3][2] += a3 * b2; c[3][3] += a3 * b3;
        }
    }
    #pragma unroll
    for (int i = 0; i < 4; ++i) {
        float4 o = make_float4(c[i][0], c[i][1], c[i][2], c[i][3]);
        *(float4*)&Cp[(size_t)(m0 + ty * 4 + i) * 512 + n0 + tx * 4] = o;
    }
}

// ---------------------------------------------------------------------------
// K2: table2[p][m][d] = sum_j tableA[p][m][j] * up_w[d][j]
//   A: [16][256][512], W: [1024][512] (row d, col j -> B transposed), C: [16][256][1024]
// ---------------------------------------------------------------------------
__global__ __launch_bounds__(256) void k2_gemm(
    const float* __restrict__ A,
    const float* __restrict__ W,
    float* __restrict__ C)
{
    const int p  = blockIdx.z;
    const int m0 = blockIdx.y * 64;
    const int n0 = blockIdx.x * 64;
    const float* __restrict__ Ap = A + (size_t)p * 256 * 512;
    float* __restrict__ Cp = C + (size_t)p * 256 * 1024;

    __shared__ float As[16][64];
    __shared__ float Bs[16][68];

    const int tid = threadIdx.x;
    const int am = tid >> 2, ak = (tid & 3) << 2;   // A: 64 rows x 16 k
    const int wn = tid >> 2, wk = (tid & 3) << 2;   // W: 64 n-rows x 16 k
    const int tx = tid & 15, ty = tid >> 4;

    float c[4][4] = {};

    for (int k0 = 0; k0 < 512; k0 += 16) {
        float4 av = *(const float4*)&Ap[(size_t)(m0 + am) * 512 + k0 + ak];
        float4 wv = *(const float4*)&W [(size_t)(n0 + wn) * 512 + k0 + wk];
        __syncthreads();
        As[ak + 0][am] = av.x;
        As[ak + 1][am] = av.y;
        As[ak + 2][am] = av.z;
        As[ak + 3][am] = av.w;
        Bs[wk + 0][wn] = wv.x;
        Bs[wk + 1][wn] = wv.y;
        Bs[wk + 2][wn] = wv.z;
        Bs[wk + 3][wn] = wv.w;
        __syncthreads();
        #pragma unroll
        for (int k = 0; k < 16; ++k) {
            float a0 = As[k][ty * 4 + 0], a1 = As[k][ty * 4 + 1];
            float a2 = As[k][ty * 4 + 2], a3 = As[k][ty * 4 + 3];
            float b0 = Bs[k][tx * 4 + 0], b1 = Bs[k][tx * 4 + 1];
            float b2 = Bs[k][tx * 4 + 2], b3 = Bs[k][tx * 4 + 3];
            c[0][0] += a0 * b0; c[0][1] += a0 * b1; c[0][2] += a0 * b2; c[0][3] += a0 * b3;
            c[1][0] += a1 * b0; c[1][1] += a1 * b1; c[1][2] += a1 * b2; c[1][3] += a1 * b3;
            c[2][0] += a2 * b0; c[2][1] += a2 * b1; c[2][2] += a2 * b2; c[2][3] += a2 * b3;
            c[3][0] += a3 * b0; c[3][1] += a3 * b1; c[3][2] += a3 * b2; c[3][3] += a3 * b3;
        }
    }
    #pragma unroll
    for (int i = 0; i < 4; ++i) {
        float4 o = make_float4(c[i][0], c[i][1], c[i][2], c[i][3]);
        *(float4*)&Cp[(size_t)(m0 + ty * 4 + i) * 1024 + n0 + tx * 4] = o;
    }
}

// ---------------------------------------------------------------------------
// K3: per row (b,s): acc[d] = up_b[d] + sum_p table2[p][ids[row][p]][d]; LayerNorm
// 256 threads/block, one block per row; each thread owns 4 consecutive d (float4).
// ids are block-uniform -> scalar loads, no divergence.
// ---------------------------------------------------------------------------
__global__ __launch_bounds__(256) void k3_gather_ln(
    const int* __restrict__ ids,      // [rows][16]
    const float* __restrict__ T,      // [16][256][1024]
    const float* __restrict__ up_b,   // [1024]
    const float* __restrict__ gamma,  // [1024]
    const float* __restrict__ beta,   // [1024]
    float* __restrict__ out)          // [rows][1024]
{
    const int row = blockIdx.x;
    const int tid = threadIdx.x;

    float4 acc = *(const float4*)&up_b[tid * 4];

    #pragma unroll
    for (int p = 0; p < 16; ++p) {
        const int id = ids[row * 16 + p];
        if (id >= 0) {
            const float4 t = *(const float4*)&T[(size_t)((p << 8) + id) * 1024 + tid * 4];
            acc.x += t.x; acc.y += t.y; acc.z += t.z; acc.w += t.w;
        }
    }

    float s  = acc.x + acc.y + acc.z + acc.w;
    float ss = acc.x * acc.x + acc.y * acc.y + acc.z * acc.z + acc.w * acc.w;
    #pragma unroll
    for (int off = 32; off > 0; off >>= 1) {
        s  += __shfl_down(s,  off, 64);
        ss += __shfl_down(ss, off, 64);
    }

    __shared__ float red[8];
    const int wid = tid >> 6, lane = tid & 63;
    if (lane == 0) { red[wid] = s; red[4 + wid] = ss; }
    __syncthreads();

    const float S   = red[0] + red[1] + red[2] + red[3];
    const float SS  = red[4] + red[5] + red[6] + red[7];
    const float mu  = S * (1.0f / 1024.0f);
    const float var = SS * (1.0f / 1024.0f) - mu * mu;
    const float rstd = rsqrtf(var + LN_EPS);

    const float4 g = *(const float4*)&gamma[tid * 4];
    const float4 b = *(const float4*)&beta[tid * 4];
    float4 o;
    o.x = (acc.x - mu) * rstd * g.x + b.x;
    o.y = (acc.y - mu) * rstd * g.y + b.y;
    o.z = (acc.z - mu) * rstd * g.z + b.z;
    o.w = (acc.w - mu) * rstd * g.w + b.w;
    *(float4*)&out[(size_t)row * 1024 + tid * 4] = o;
}

extern "C" void kernel_launch(void* const* d_in, const int* in_sizes, int n_in,
                              void* d_out, int out_size, void* d_ws, size_t ws_size,
                              hipStream_t stream) {
    const int*   ids      = (const int*)d_in[0];
    const float* byte_emb = (const float*)d_in[1];
    const float* pos_emb  = (const float*)d_in[2];
    const float* up_w     = (const float*)d_in[3];
    const float* up_b     = (const float*)d_in[4];
    const float* gamma    = (const float*)d_in[5];
    const float* beta     = (const float*)d_in[6];
    float* out = (float*)d_out;

    float* tableA = (float*)d_ws;                  // [16][256][512]  = 8 MB
    float* table2 = tableA + 16 * 256 * 512;       // [16][256][1024] = 16 MB

    const int rows = in_sizes[0] / 16;             // B*S = 8192

    dim3 g1(512 / 64, 256 / 64, 16);               // (8,4,16)
    k1_gemm<<<g1, 256, 0, stream>>>(byte_emb, pos_emb, tableA);

    dim3 g2(1024 / 64, 256 / 64, 16);              // (16,4,16)
    k2_gemm<<<g2, 256, 0, stream>>>(tableA, up_w, table2);

    k3_gather_ln<<<rows, 256, 0, stream>>>(ids, table2, up_b, gamma, beta, out);
}

// Round 2
// 103.059 us; speedup vs baseline: 1.5291x; 1.5291x over previous
//
#include <hip/hip_runtime.h>
#include <hip/hip_bf16.h>

#define LN_EPS 1e-5f

typedef __attribute__((ext_vector_type(8))) short short8;
typedef __attribute__((ext_vector_type(4))) float floatx4;

__device__ __forceinline__ unsigned short f2bf(float f) {
    __hip_bfloat16 h = __float2bfloat16(f);
    return __builtin_bit_cast(unsigned short, h);
}
__device__ __forceinline__ float bf2f(unsigned short u) {
    return __builtin_bit_cast(float, (unsigned int)u << 16);
}

// ---------------------------------------------------------------------------
// K0: cast up_w [1024][512] fp32 -> bf16 bits (row-major unchanged)
// ---------------------------------------------------------------------------
__global__ __launch_bounds__(256) void k_cast(
    const float* __restrict__ W, unsigned short* __restrict__ Wb)
{
    const int i = (blockIdx.x * 256 + threadIdx.x) * 4;
    const float4 v = *(const float4*)&W[i];
    ushort4 o;
    o.x = f2bf(v.x); o.y = f2bf(v.y); o.z = f2bf(v.z); o.w = f2bf(v.w);
    *(ushort4*)&Wb[i] = o;
}

// ---------------------------------------------------------------------------
// K1: tableA[p][m][j] = sum_i byte_emb[m][i] * pos_emb[p][i][j]  (fp32 compute,
// bf16 output). 64x64 tile, BK=16, 256 threads, 4x4 per thread.
// ---------------------------------------------------------------------------
__global__ __launch_bounds__(256) void k1_gemm(
    const float* __restrict__ A,
    const float* __restrict__ B,
    unsigned short* __restrict__ C)
{
    const int p  = blockIdx.z;
    const int m0 = blockIdx.y * 64;
    const int n0 = blockIdx.x * 64;
    const float* __restrict__ Bp = B + (size_t)p * 512 * 512;
    unsigned short* __restrict__ Cp = C + (size_t)p * 256 * 512;

    __shared__ float As[16][64];
    __shared__ float Bs[16][68];

    const int tid = threadIdx.x;
    const int am = tid >> 2, ak = (tid & 3) << 2;
    const int bk = tid >> 4, bn = (tid & 15) << 2;
    const int tx = tid & 15, ty = tid >> 4;

    float c[4][4] = {};

    for (int k0 = 0; k0 < 512; k0 += 16) {
        float4 av = *(const float4*)&A [(m0 + am) * 512 + k0 + ak];
        float4 bv = *(const float4*)&Bp[(size_t)(k0 + bk) * 512 + n0 + bn];
        __syncthreads();
        As[ak + 0][am] = av.x;
        As[ak + 1][am] = av.y;
        As[ak + 2][am] = av.z;
        As[ak + 3][am] = av.w;
        *(float4*)&Bs[bk][bn] = bv;
        __syncthreads();
        #pragma unroll
        for (int k = 0; k < 16; ++k) {
            float a0 = As[k][ty * 4 + 0], a1 = As[k][ty * 4 + 1];
            float a2 = As[k][ty * 4 + 2], a3 = As[k][ty * 4 + 3];
            float b0 = Bs[k][tx * 4 + 0], b1 = Bs[k][tx * 4 + 1];
            float b2 = Bs[k][tx * 4 + 2], b3 = Bs[k][tx * 4 + 3];
            c[0][0] += a0 * b0; c[0][1] += a0 * b1; c[0][2] += a0 * b2; c[0][3] += a0 * b3;
            c[1][0] += a1 * b0; c[1][1] += a1 * b1; c[1][2] += a1 * b2; c[1][3] += a1 * b3;
            c[2][0] += a2 * b0; c[2][1] += a2 * b1; c[2][2] += a2 * b2; c[2][3] += a2 * b3;
            c[3][0] += a3 * b0; c[3][1] += a3 * b1; c[3][2] += a3 * b2; c[3][3] += a3 * b3;
        }
    }
    #pragma unroll
    for (int i = 0; i < 4; ++i) {
        ushort4 o;
        o.x = f2bf(c[i][0]); o.y = f2bf(c[i][1]);
        o.z = f2bf(c[i][2]); o.w = f2bf(c[i][3]);
        *(ushort4*)&Cp[(size_t)(m0 + ty * 4 + i) * 512 + n0 + tx * 4] = o;
    }
}

// ---------------------------------------------------------------------------
// K2: gather+sum. e_pre[row][j] = sum_p tableA[p][ids[row][p]][j]  (bf16 out,
// fp32 accum). One wave per row; each lane owns 8 consecutive j (16B).
// ---------------------------------------------------------------------------
__global__ __launch_bounds__(256) void k_gather(
    const int* __restrict__ ids,
    const unsigned short* __restrict__ T,   // [16][256][512] bf16
    unsigned short* __restrict__ e_pre)     // [rows][512] bf16
{
    const int row  = blockIdx.x * 4 + (threadIdx.x >> 6);
    const int lane = threadIdx.x & 63;
    const int* __restrict__ idr = ids + row * 16;

    float acc[8] = {};
    #pragma unroll
    for (int p = 0; p < 16; ++p) {
        const int id = idr[p];
        if (id >= 0) {
            const short8 v = *(const short8*)&T[(size_t)((p << 8) + id) * 512 + lane * 8];
            #pragma unroll
            for (int j = 0; j < 8; ++j)
                acc[j] += bf2f((unsigned short)v[j]);
        }
    }
    short8 r;
    #pragma unroll
    for (int j = 0; j < 8; ++j) r[j] = (short)f2bf(acc[j]);
    *(short8*)&e_pre[(size_t)row * 512 + lane * 8] = r;
}

// ---------------------------------------------------------------------------
// K3: E[row][d] = up_b[d] + sum_j e_pre[row][j] * up_w[d][j]   (bf16 MFMA)
// Block 256 thr = 4 waves (2x2), wave tile 64x64, block tile 128x128.
// Direct-from-global fragments (operands are L2-resident: 8MB + 1MB).
// ---------------------------------------------------------------------------
__global__ __launch_bounds__(256) void k_mfma(
    const unsigned short* __restrict__ A,   // e_pre [8192][512] bf16
    const unsigned short* __restrict__ Bw,  // up_w  [1024][512] bf16
    const float* __restrict__ up_b,         // [1024]
    float* __restrict__ E)                  // [8192][1024] fp32 (= d_out)
{
    const int tid  = threadIdx.x;
    const int w    = tid >> 6, lane = tid & 63;
    const int wr   = w >> 1,   wc   = w & 1;
    const int m0   = blockIdx.y * 128 + wr * 64;
    const int n0   = blockIdx.x * 128 + wc * 64;
    const int lr   = lane & 15;
    const int lk   = (lane >> 4) * 8;

    floatx4 acc[4][4] = {};

    for (int k0 = 0; k0 < 512; k0 += 32) {
        short8 a[4], b[4];
        #pragma unroll
        for (int i = 0; i < 4; ++i)
            a[i] = *(const short8*)&A[(size_t)(m0 + i * 16 + lr) * 512 + k0 + lk];
        #pragma unroll
        for (int i = 0; i < 4; ++i)
            b[i] = *(const short8*)&Bw[(size_t)(n0 + i * 16 + lr) * 512 + k0 + lk];
        #pragma unroll
        for (int mi = 0; mi < 4; ++mi)
            #pragma unroll
            for (int ni = 0; ni < 4; ++ni)
                acc[mi][ni] = __builtin_amdgcn_mfma_f32_16x16x32_bf16(
                    a[mi], b[ni], acc[mi][ni], 0, 0, 0);
    }

    const int orow = (lane >> 4) * 4;
    #pragma unroll
    for (int ni = 0; ni < 4; ++ni) {
        const int col = n0 + ni * 16 + lr;
        const float bias = up_b[col];
        #pragma unroll
        for (int mi = 0; mi < 4; ++mi)
            #pragma unroll
            for (int r = 0; r < 4; ++r)
                E[(size_t)(m0 + mi * 16 + orow + r) * 1024 + col] = acc[mi][ni][r] + bias;
    }
}

// ---------------------------------------------------------------------------
// K4: in-place LayerNorm over d_out rows of 1024. Block per row, 256 threads,
// each thread owns 4 consecutive d.
// ---------------------------------------------------------------------------
__global__ __launch_bounds__(256) void k_ln(
    const float* __restrict__ gamma,
    const float* __restrict__ beta,
    float* __restrict__ out)
{
    const int row = blockIdx.x;
    const int tid = threadIdx.x;

    float4 acc = *(const float4*)&out[(size_t)row * 1024 + tid * 4];

    float s  = acc.x + acc.y + acc.z + acc.w;
    float ss = acc.x * acc.x + acc.y * acc.y + acc.z * acc.z + acc.w * acc.w;
    #pragma unroll
    for (int off = 32; off > 0; off >>= 1) {
        s  += __shfl_down(s,  off, 64);
        ss += __shfl_down(ss, off, 64);
    }

    __shared__ float red[8];
    const int wid = tid >> 6, lane = tid & 63;
    if (lane == 0) { red[wid] = s; red[4 + wid] = ss; }
    __syncthreads();

    const float S   = red[0] + red[1] + red[2] + red[3];
    const float SS  = red[4] + red[5] + red[6] + red[7];
    const float mu  = S * (1.0f / 1024.0f);
    const float var = SS * (1.0f / 1024.0f) - mu * mu;
    const float rstd = rsqrtf(var + LN_EPS);

    const float4 g = *(const float4*)&gamma[tid * 4];
    const float4 b = *(const float4*)&beta[tid * 4];
    float4 o;
    o.x = (acc.x - mu) * rstd * g.x + b.x;
    o.y = (acc.y - mu) * rstd * g.y + b.y;
    o.z = (acc.z - mu) * rstd * g.z + b.z;
    o.w = (acc.w - mu) * rstd * g.w + b.w;
    *(float4*)&out[(size_t)row * 1024 + tid * 4] = o;
}

extern "C" void kernel_launch(void* const* d_in, const int* in_sizes, int n_in,
                              void* d_out, int out_size, void* d_ws, size_t ws_size,
                              hipStream_t stream) {
    const int*   ids      = (const int*)d_in[0];
    const float* byte_emb = (const float*)d_in[1];
    const float* pos_emb  = (const float*)d_in[2];
    const float* up_w     = (const float*)d_in[3];
    const float* up_b     = (const float*)d_in[4];
    const float* gamma    = (const float*)d_in[5];
    const float* beta     = (const float*)d_in[6];
    float* out = (float*)d_out;

    // ws layout (bf16 bits as unsigned short):
    //   [0, 1MB)   up_w_bf16 [1024][512]
    //   [1MB, 5MB) tableA    [16][256][512]
    //   [5MB,13MB) e_pre     [8192][512]
    unsigned short* wb     = (unsigned short*)d_ws;
    unsigned short* tableA = wb + (size_t)1024 * 512;
    unsigned short* e_pre  = tableA + (size_t)16 * 256 * 512;

    const int rows = in_sizes[0] / 16;             // B*S = 8192

    k_cast<<<512, 256, 0, stream>>>(up_w, wb);     // 1024*512/4/256

    dim3 g1(512 / 64, 256 / 64, 16);
    k1_gemm<<<g1, 256, 0, stream>>>(byte_emb, pos_emb, tableA);

    k_gather<<<rows / 4, 256, 0, stream>>>(ids, tableA, e_pre);

    dim3 g3(1024 / 128, rows / 128);
    k_mfma<<<g3, 256, 0, stream>>>(e_pre, wb, up_b, out);

    k_ln<<<rows, 256, 0, stream>>>(gamma, beta, out);
}

// Round 3
// 90.805 us; speedup vs baseline: 1.7355x; 1.1349x over previous
//
#include <hip/hip_runtime.h>
#include <hip/hip_bf16.h>

#define LN_EPS 1e-5f

typedef __attribute__((ext_vector_type(8))) short short8;
typedef __attribute__((ext_vector_type(4))) float floatx4;

__device__ __forceinline__ unsigned short f2bf(float f) {
    __hip_bfloat16 h = __float2bfloat16(f);
    return __builtin_bit_cast(unsigned short, h);
}
__device__ __forceinline__ float bf2f(unsigned short u) {
    return __builtin_bit_cast(float, (unsigned int)u << 16);
}

// ---------------------------------------------------------------------------
// K0: flat cast fp32 -> bf16 (byte_emb, up_w)
// ---------------------------------------------------------------------------
__global__ __launch_bounds__(256) void k_cast(
    const float* __restrict__ W, unsigned short* __restrict__ Wb)
{
    const int i = (blockIdx.x * 256 + threadIdx.x) * 4;
    const float4 v = *(const float4*)&W[i];
    ushort4 o;
    o.x = f2bf(v.x); o.y = f2bf(v.y); o.z = f2bf(v.z); o.w = f2bf(v.w);
    *(ushort4*)&Wb[i] = o;
}

// ---------------------------------------------------------------------------
// K0b: transpose-cast pos_emb [16][512][512] f32 -> posT bf16, posT[p][j][i].
// 64x64 LDS tile, pad 65 (scalar LDS r/w, worst 2-way bank alias = free).
// ---------------------------------------------------------------------------
__global__ __launch_bounds__(256) void k_castT(
    const float* __restrict__ P,
    unsigned short* __restrict__ PT)
{
    const int p  = blockIdx.z;
    const int i0 = blockIdx.y * 64;
    const int j0 = blockIdx.x * 64;
    const float* __restrict__ Pp = P + (size_t)p * 512 * 512;
    unsigned short* __restrict__ Tp = PT + (size_t)p * 512 * 512;

    __shared__ float S[64][65];
    const int r  = threadIdx.x >> 2;        // 0..63
    const int c0 = (threadIdx.x & 3) * 16;  // 0,16,32,48

    #pragma unroll
    for (int c = 0; c < 16; c += 4) {
        const float4 v = *(const float4*)&Pp[(size_t)(i0 + r) * 512 + j0 + c0 + c];
        S[r][c0 + c + 0] = v.x;
        S[r][c0 + c + 1] = v.y;
        S[r][c0 + c + 2] = v.z;
        S[r][c0 + c + 3] = v.w;
    }
    __syncthreads();

    #pragma unroll
    for (int h = 0; h < 2; ++h) {
        short8 o;
        #pragma unroll
        for (int k = 0; k < 8; ++k)
            o[k] = (short)f2bf(S[c0 + h * 8 + k][r]);
        *(short8*)&Tp[(size_t)(j0 + r) * 512 + i0 + c0 + h * 8] = o;
    }
}

// ---------------------------------------------------------------------------
// K1: tableA[p][m][j] = sum_i byte_emb[m][i] * posT[p][j][i]   (bf16 MFMA)
// One wave per block, wave tile 64x64, direct-from-global fragments.
// ---------------------------------------------------------------------------
__global__ __launch_bounds__(64) void k1_mfma(
    const unsigned short* __restrict__ A,   // byte_emb bf16 [256][512]
    const unsigned short* __restrict__ PT,  // posT bf16 [16][512][512]
    unsigned short* __restrict__ T)         // tableA bf16 [16][256][512]
{
    const int p  = blockIdx.z;
    const int m0 = blockIdx.y * 64;
    const int n0 = blockIdx.x * 64;
    const unsigned short* __restrict__ Bp = PT + (size_t)p * 512 * 512;
    unsigned short* __restrict__ Tp = T + (size_t)p * 256 * 512;

    const int lane = threadIdx.x & 63;
    const int lr = lane & 15;
    const int lk = (lane >> 4) * 8;

    floatx4 acc[4][4] = {};

    for (int k0 = 0; k0 < 512; k0 += 32) {
        short8 a[4], b[4];
        #pragma unroll
        for (int i = 0; i < 4; ++i)
            a[i] = *(const short8*)&A [(size_t)(m0 + i * 16 + lr) * 512 + k0 + lk];
        #pragma unroll
        for (int i = 0; i < 4; ++i)
            b[i] = *(const short8*)&Bp[(size_t)(n0 + i * 16 + lr) * 512 + k0 + lk];
        #pragma unroll
        for (int mi = 0; mi < 4; ++mi)
            #pragma unroll
            for (int ni = 0; ni < 4; ++ni)
                acc[mi][ni] = __builtin_amdgcn_mfma_f32_16x16x32_bf16(
                    a[mi], b[ni], acc[mi][ni], 0, 0, 0);
    }

    const int orow = (lane >> 4) * 4;
    #pragma unroll
    for (int ni = 0; ni < 4; ++ni)
        #pragma unroll
        for (int mi = 0; mi < 4; ++mi)
            #pragma unroll
            for (int r = 0; r < 4; ++r)
                Tp[(size_t)(m0 + mi * 16 + orow + r) * 512 + n0 + ni * 16 + lr]
                    = f2bf(acc[mi][ni][r]);
}

// ---------------------------------------------------------------------------
// K2: gather+sum. e_pre[row][j] = sum_p tableA[p][ids[row][p]][j]  (bf16 out,
// fp32 accum). One wave per row; each lane owns 8 consecutive j (16B).
// ---------------------------------------------------------------------------
__global__ __launch_bounds__(256) void k_gather(
    const int* __restrict__ ids,
    const unsigned short* __restrict__ T,   // [16][256][512] bf16
    unsigned short* __restrict__ e_pre)     // [rows][512] bf16
{
    const int row  = blockIdx.x * 4 + (threadIdx.x >> 6);
    const int lane = threadIdx.x & 63;
    const int* __restrict__ idr = ids + row * 16;

    float acc[8] = {};
    #pragma unroll
    for (int p = 0; p < 16; ++p) {
        const int id = idr[p];
        if (id >= 0) {
            const short8 v = *(const short8*)&T[(size_t)((p << 8) + id) * 512 + lane * 8];
            #pragma unroll
            for (int j = 0; j < 8; ++j)
                acc[j] += bf2f((unsigned short)v[j]);
        }
    }
    short8 r;
    #pragma unroll
    for (int j = 0; j < 8; ++j) r[j] = (short)f2bf(acc[j]);
    *(short8*)&e_pre[(size_t)row * 512 + lane * 8] = r;
}

// ---------------------------------------------------------------------------
// K3: E[row][d] = up_b[d] + sum_j e_pre[row][j] * up_w[d][j]   (bf16 MFMA)
// Block 256 thr = 4 waves (2x2), wave tile 64x64, block tile 128x128.
// ---------------------------------------------------------------------------
__global__ __launch_bounds__(256) void k_mfma(
    const unsigned short* __restrict__ A,   // e_pre [8192][512] bf16
    const unsigned short* __restrict__ Bw,  // up_w  [1024][512] bf16
    const float* __restrict__ up_b,         // [1024]
    float* __restrict__ E)                  // [8192][1024] fp32 (= d_out)
{
    const int tid  = threadIdx.x;
    const int w    = tid >> 6, lane = tid & 63;
    const int wr   = w >> 1,   wc   = w & 1;
    const int m0   = blockIdx.y * 128 + wr * 64;
    const int n0   = blockIdx.x * 128 + wc * 64;
    const int lr   = lane & 15;
    const int lk   = (lane >> 4) * 8;

    floatx4 acc[4][4] = {};

    for (int k0 = 0; k0 < 512; k0 += 32) {
        short8 a[4], b[4];
        #pragma unroll
        for (int i = 0; i < 4; ++i)
            a[i] = *(const short8*)&A[(size_t)(m0 + i * 16 + lr) * 512 + k0 + lk];
        #pragma unroll
        for (int i = 0; i < 4; ++i)
            b[i] = *(const short8*)&Bw[(size_t)(n0 + i * 16 + lr) * 512 + k0 + lk];
        #pragma unroll
        for (int mi = 0; mi < 4; ++mi)
            #pragma unroll
            for (int ni = 0; ni < 4; ++ni)
                acc[mi][ni] = __builtin_amdgcn_mfma_f32_16x16x32_bf16(
                    a[mi], b[ni], acc[mi][ni], 0, 0, 0);
    }

    const int orow = (lane >> 4) * 4;
    #pragma unroll
    for (int ni = 0; ni < 4; ++ni) {
        const int col = n0 + ni * 16 + lr;
        const float bias = up_b[col];
        #pragma unroll
        for (int mi = 0; mi < 4; ++mi)
            #pragma unroll
            for (int r = 0; r < 4; ++r)
                E[(size_t)(m0 + mi * 16 + orow + r) * 1024 + col] = acc[mi][ni][r] + bias;
    }
}

// ---------------------------------------------------------------------------
// K4: in-place LayerNorm over d_out rows of 1024.
// ---------------------------------------------------------------------------
__global__ __launch_bounds__(256) void k_ln(
    const float* __restrict__ gamma,
    const float* __restrict__ beta,
    float* __restrict__ out)
{
    const int row = blockIdx.x;
    const int tid = threadIdx.x;

    float4 acc = *(const float4*)&out[(size_t)row * 1024 + tid * 4];

    float s  = acc.x + acc.y + acc.z + acc.w;
    float ss = acc.x * acc.x + acc.y * acc.y + acc.z * acc.z + acc.w * acc.w;
    #pragma unroll
    for (int off = 32; off > 0; off >>= 1) {
        s  += __shfl_down(s,  off, 64);
        ss += __shfl_down(ss, off, 64);
    }

    __shared__ float red[8];
    const int wid = tid >> 6, lane = tid & 63;
    if (lane == 0) { red[wid] = s; red[4 + wid] = ss; }
    __syncthreads();

    const float S   = red[0] + red[1] + red[2] + red[3];
    const float SS  = red[4] + red[5] + red[6] + red[7];
    const float mu  = S * (1.0f / 1024.0f);
    const float var = SS * (1.0f / 1024.0f) - mu * mu;
    const float rstd = rsqrtf(var + LN_EPS);

    const float4 g = *(const float4*)&gamma[tid * 4];
    const float4 b = *(const float4*)&beta[tid * 4];
    float4 o;
    o.x = (acc.x - mu) * rstd * g.x + b.x;
    o.y = (acc.y - mu) * rstd * g.y + b.y;
    o.z = (acc.z - mu) * rstd * g.z + b.z;
    o.w = (acc.w - mu) * rstd * g.w + b.w;
    *(float4*)&out[(size_t)row * 1024 + tid * 4] = o;
}

extern "C" void kernel_launch(void* const* d_in, const int* in_sizes, int n_in,
                              void* d_out, int out_size, void* d_ws, size_t ws_size,
                              hipStream_t stream) {
    const int*   ids      = (const int*)d_in[0];
    const float* byte_emb = (const float*)d_in[1];
    const float* pos_emb  = (const float*)d_in[2];
    const float* up_w     = (const float*)d_in[3];
    const float* up_b     = (const float*)d_in[4];
    const float* gamma    = (const float*)d_in[5];
    const float* beta     = (const float*)d_in[6];
    float* out = (float*)d_out;

    // ws layout (bf16 bits as unsigned short):
    //   wb     up_w_bf16 [1024][512]       1 MB
    //   bb     byte_emb  [256][512]        0.25 MB
    //   posT   [16][512][512] ([p][j][i])  8 MB
    //   tableA [16][256][512]              4 MB
    //   e_pre  [8192][512]                 8 MB
    unsigned short* wb     = (unsigned short*)d_ws;
    unsigned short* bb     = wb + (size_t)1024 * 512;
    unsigned short* posT   = bb + (size_t)256 * 512;
    unsigned short* tableA = posT + (size_t)16 * 512 * 512;
    unsigned short* e_pre  = tableA + (size_t)16 * 256 * 512;

    const int rows = in_sizes[0] / 16;             // B*S = 8192

    k_cast<<<512, 256, 0, stream>>>(up_w, wb);
    k_cast<<<128, 256, 0, stream>>>(byte_emb, bb);

    dim3 gt(8, 8, 16);
    k_castT<<<gt, 256, 0, stream>>>(pos_emb, posT);

    dim3 g1(8, 4, 16);                             // n=512/64, m=256/64, p
    k1_mfma<<<g1, 64, 0, stream>>>(bb, posT, tableA);

    k_gather<<<rows / 4, 256, 0, stream>>>(ids, tableA, e_pre);

    dim3 g3(1024 / 128, rows / 128);
    k_mfma<<<g3, 256, 0, stream>>>(e_pre, wb, up_b, out);

    k_ln<<<rows, 256, 0, stream>>>(gamma, beta, out);
}

// Round 4
// 76.535 us; speedup vs baseline: 2.0590x; 1.1865x over previous
//
#include <hip/hip_runtime.h>
#include <hip/hip_bf16.h>

#define LN_EPS 1e-5f

typedef __attribute__((ext_vector_type(8))) short short8;
typedef __attribute__((ext_vector_type(4))) float floatx4;

static __device__ __forceinline__ unsigned int f2bfu(float f) {
    __hip_bfloat16 h = __float2bfloat16(f);
    return (unsigned int)__builtin_bit_cast(unsigned short, h);
}
static __device__ __forceinline__ float bf2f_lo(unsigned int u) {
    return __builtin_bit_cast(float, (u & 0xffffu) << 16);
}
static __device__ __forceinline__ float bf2f_hi(unsigned int u) {
    return __builtin_bit_cast(float, u & 0xffff0000u);
}

// ---------------------------------------------------------------------------
// k_prep: cast up_w [1024][512] and byte_emb [256][512] fp32 -> bf16.
// blocks 0..511 -> up_w (524288 elems), 512..639 -> byte_emb (131072 elems).
// ---------------------------------------------------------------------------
__global__ __launch_bounds__(256) void k_prep(
    const float* __restrict__ up_w, const float* __restrict__ byte_emb,
    unsigned short* __restrict__ wb, unsigned short* __restrict__ bb)
{
    const int b = blockIdx.x;
    const float* src;
    unsigned short* dst;
    int idx;
    if (b < 512) { src = up_w;     dst = wb; idx = (b * 256 + threadIdx.x) * 4; }
    else         { src = byte_emb; dst = bb; idx = ((b - 512) * 256 + threadIdx.x) * 4; }
    const float4 v = *(const float4*)&src[idx];
    ushort4 o;
    o.x = (unsigned short)f2bfu(v.x); o.y = (unsigned short)f2bfu(v.y);
    o.z = (unsigned short)f2bfu(v.z); o.w = (unsigned short)f2bfu(v.w);
    *(ushort4*)&dst[idx] = o;
}

// ---------------------------------------------------------------------------
// k1_t: tableA[p][m][j] = sum_i bb[m][i] * pos_emb[p][i][j]   (bf16 MFMA)
// pos_emb fp32 [i][j] is transposed+cast through LDS per 32-i step.
// Block: 256 thr = 4 waves (2m x 2j), wave tile 32x32; block tile 64m x 64j.
// Grid (512/64 j, 256/64 m, 16 p) = (8,4,16) -> 512 blocks, 8 waves/CU.
// ---------------------------------------------------------------------------
__global__ __launch_bounds__(256) void k1_t(
    const unsigned short* __restrict__ A,   // bb [256][512] bf16
    const float* __restrict__ P,            // pos_emb [16][512][512] f32
    unsigned short* __restrict__ T)         // tableA [16][256][512] bf16
{
    const int p  = blockIdx.z;
    const int j0 = blockIdx.x * 64;
    const int m0 = blockIdx.y * 64;
    const float* __restrict__ Pp = P + (size_t)p * 512 * 512;
    unsigned short* __restrict__ Tp = T + (size_t)p * 256 * 512;

    __shared__ unsigned short Bs[64][40];   // Bs[j][i], 80B row (16B aligned)

    const int tid  = threadIdx.x;
    const int w    = tid >> 6, lane = tid & 63;
    const int lr   = lane & 15, lg = lane >> 4, lk = lg * 8;
    const int wr   = w >> 1, wc = w & 1;    // m-half, j-half
    const int jg   = tid & 15;              // j quad: j = 4*jg..+3
    const int ip   = tid >> 4;              // i pair: i = 2*ip, 2*ip+1

    floatx4 acc[2][2] = {};

    for (int k0 = 0; k0 < 512; k0 += 32) {
        const float4 v0 = *(const float4*)&Pp[(size_t)(k0 + 2 * ip)     * 512 + j0 + 4 * jg];
        const float4 v1 = *(const float4*)&Pp[(size_t)(k0 + 2 * ip + 1) * 512 + j0 + 4 * jg];
        __syncthreads();   // previous iteration's reads done
        *(unsigned int*)&Bs[4 * jg + 0][2 * ip] = f2bfu(v0.x) | (f2bfu(v1.x) << 16);
        *(unsigned int*)&Bs[4 * jg + 1][2 * ip] = f2bfu(v0.y) | (f2bfu(v1.y) << 16);
        *(unsigned int*)&Bs[4 * jg + 2][2 * ip] = f2bfu(v0.z) | (f2bfu(v1.z) << 16);
        *(unsigned int*)&Bs[4 * jg + 3][2 * ip] = f2bfu(v0.w) | (f2bfu(v1.w) << 16);
        __syncthreads();

        short8 a[2], b[2];
        #pragma unroll
        for (int mf = 0; mf < 2; ++mf)
            a[mf] = *(const short8*)&A[(size_t)(m0 + wr * 32 + mf * 16 + lr) * 512 + k0 + lk];
        #pragma unroll
        for (int nf = 0; nf < 2; ++nf)
            b[nf] = *(const short8*)&Bs[wc * 32 + nf * 16 + lr][lk];
        #pragma unroll
        for (int mf = 0; mf < 2; ++mf)
            #pragma unroll
            for (int nf = 0; nf < 2; ++nf)
                acc[mf][nf] = __builtin_amdgcn_mfma_f32_16x16x32_bf16(
                    a[mf], b[nf], acc[mf][nf], 0, 0, 0);
    }

    #pragma unroll
    for (int nf = 0; nf < 2; ++nf)
        #pragma unroll
        for (int mf = 0; mf < 2; ++mf)
            #pragma unroll
            for (int q = 0; q < 4; ++q)
                Tp[(size_t)(m0 + wr * 32 + mf * 16 + lg * 4 + q) * 512
                   + j0 + wc * 32 + nf * 16 + lr]
                    = (unsigned short)f2bfu(acc[mf][nf][q]);
}

// ---------------------------------------------------------------------------
// k_fused: gather + up-projection + LayerNorm.
//   Block = 32 rows x 1024 cols, 512 thr (8 waves; wave w -> cols w*128..+127,
//   wave tile 32x128). Per 32-k step: 512 threads gather-sum 16 table slices
//   into A_lds (fp32 accum -> bf16), then MFMA vs up_w fragments from global.
//   Epilogue: bias + row-LN (16-lane shuffle + cross-wave LDS reduce).
// ---------------------------------------------------------------------------
__global__ __launch_bounds__(512) void k_fused(
    const int* __restrict__ ids,            // [rows][16]
    const unsigned short* __restrict__ T,   // tableA [16][256][512] bf16
    const unsigned short* __restrict__ Bw,  // up_w [1024][512] bf16
    const float* __restrict__ up_b,
    const float* __restrict__ gamma,
    const float* __restrict__ beta,
    float* __restrict__ out)                // [rows][1024] f32
{
    const int r0   = blockIdx.x * 32;
    const int tid  = threadIdx.x;
    const int w    = tid >> 6, lane = tid & 63;
    const int lr   = lane & 15, lg = lane >> 4, lk = lg * 8;

    __shared__ unsigned short A_lds[32][40];   // [row][k], 80B row
    __shared__ int   ids_s[512];
    __shared__ float redS[32][9], redQ[32][9];

    ids_s[tid] = ids[r0 * 16 + tid];
    __syncthreads();

    const int grow = tid >> 4, gc = tid & 15;  // gather: row, k-pair index
    unsigned int goff[16];
    float gmask[16];
    #pragma unroll
    for (int p = 0; p < 16; ++p) {
        const int id = ids_s[grow * 16 + p];
        gmask[p] = (id >= 0) ? 1.0f : 0.0f;
        goff[p]  = (unsigned int)(((p << 8) + (id >= 0 ? id : 0)) * 512);
    }

    floatx4 acc[2][8] = {};

    for (int k0 = 0; k0 < 512; k0 += 32) {
        float f0 = 0.0f, f1 = 0.0f;
        #pragma unroll
        for (int p = 0; p < 16; ++p) {
            const unsigned int u = *(const unsigned int*)&T[goff[p] + k0 + 2 * gc];
            f0 += gmask[p] * bf2f_lo(u);
            f1 += gmask[p] * bf2f_hi(u);
        }
        __syncthreads();   // previous iteration's A_lds reads done
        *(unsigned int*)&A_lds[grow][2 * gc] = f2bfu(f0) | (f2bfu(f1) << 16);
        __syncthreads();

        short8 a[2], b[8];
        #pragma unroll
        for (int mf = 0; mf < 2; ++mf)
            a[mf] = *(const short8*)&A_lds[mf * 16 + lr][lk];
        #pragma unroll
        for (int nf = 0; nf < 8; ++nf)
            b[nf] = *(const short8*)&Bw[(size_t)(w * 128 + nf * 16 + lr) * 512 + k0 + lk];
        #pragma unroll
        for (int mf = 0; mf < 2; ++mf)
            #pragma unroll
            for (int nf = 0; nf < 8; ++nf)
                acc[mf][nf] = __builtin_amdgcn_mfma_f32_16x16x32_bf16(
                    a[mf], b[nf], acc[mf][nf], 0, 0, 0);
    }

    // bias
    #pragma unroll
    for (int nf = 0; nf < 8; ++nf) {
        const float bias = up_b[w * 128 + nf * 16 + lr];
        #pragma unroll
        for (int mf = 0; mf < 2; ++mf)
            #pragma unroll
            for (int q = 0; q < 4; ++q)
                acc[mf][nf][q] += bias;
    }

    // per-lane partial sums over this wave's 128 cols, per owned row
    float s[2][4], ss[2][4];
    #pragma unroll
    for (int mf = 0; mf < 2; ++mf)
        #pragma unroll
        for (int q = 0; q < 4; ++q) {
            float t1 = 0.0f, t2 = 0.0f;
            #pragma unroll
            for (int nf = 0; nf < 8; ++nf) {
                const float v = acc[mf][nf][q];
                t1 += v; t2 += v * v;
            }
            #pragma unroll
            for (int off = 1; off < 16; off <<= 1) {
                t1 += __shfl_xor(t1, off, 16);
                t2 += __shfl_xor(t2, off, 16);
            }
            s[mf][q] = t1; ss[mf][q] = t2;
        }

    if (lr == 0) {
        #pragma unroll
        for (int mf = 0; mf < 2; ++mf)
            #pragma unroll
            for (int q = 0; q < 4; ++q) {
                const int row = mf * 16 + lg * 4 + q;
                redS[row][w] = s[mf][q];
                redQ[row][w] = ss[mf][q];
            }
    }
    __syncthreads();

    float mu[2][4], rs[2][4];
    #pragma unroll
    for (int mf = 0; mf < 2; ++mf)
        #pragma unroll
        for (int q = 0; q < 4; ++q) {
            const int row = mf * 16 + lg * 4 + q;
            float S = 0.0f, SS = 0.0f;
            #pragma unroll
            for (int ww = 0; ww < 8; ++ww) { S += redS[row][ww]; SS += redQ[row][ww]; }
            const float m = S * (1.0f / 1024.0f);
            const float var = SS * (1.0f / 1024.0f) - m * m;
            mu[mf][q] = m;
            rs[mf][q] = rsqrtf(var + LN_EPS);
        }

    #pragma unroll
    for (int nf = 0; nf < 8; ++nf) {
        const int col = w * 128 + nf * 16 + lr;
        const float g  = gamma[col];
        const float be = beta[col];
        #pragma unroll
        for (int mf = 0; mf < 2; ++mf)
            #pragma unroll
            for (int q = 0; q < 4; ++q) {
                const int row = mf * 16 + lg * 4 + q;
                out[(size_t)(r0 + row) * 1024 + col]
                    = (acc[mf][nf][q] - mu[mf][q]) * rs[mf][q] * g + be;
            }
    }
}

extern "C" void kernel_launch(void* const* d_in, const int* in_sizes, int n_in,
                              void* d_out, int out_size, void* d_ws, size_t ws_size,
                              hipStream_t stream) {
    const int*   ids      = (const int*)d_in[0];
    const float* byte_emb = (const float*)d_in[1];
    const float* pos_emb  = (const float*)d_in[2];
    const float* up_w     = (const float*)d_in[3];
    const float* up_b     = (const float*)d_in[4];
    const float* gamma    = (const float*)d_in[5];
    const float* beta     = (const float*)d_in[6];
    float* out = (float*)d_out;

    // ws: wb [1024][512] 1MB | bb [256][512] 0.25MB | tableA [16][256][512] 4MB
    unsigned short* wb     = (unsigned short*)d_ws;
    unsigned short* bb     = wb + (size_t)1024 * 512;
    unsigned short* tableA = bb + (size_t)256 * 512;

    const int rows = in_sizes[0] / 16;   // 8192

    k_prep<<<640, 256, 0, stream>>>(up_w, byte_emb, wb, bb);

    dim3 g1(8, 4, 16);
    k1_t<<<g1, 256, 0, stream>>>(bb, pos_emb, tableA);

    k_fused<<<rows / 32, 512, 0, stream>>>(ids, tableA, wb, up_b, gamma, beta, out);
}

// Round 5
// 73.889 us; speedup vs baseline: 2.1328x; 1.0358x over previous
//
#include <hip/hip_runtime.h>
#include <hip/hip_bf16.h>

#define LN_EPS 1e-5f

typedef __attribute__((ext_vector_type(8))) short short8;
typedef __attribute__((ext_vector_type(4))) float floatx4;

static __device__ __forceinline__ unsigned int f2bfu(float f) {
    __hip_bfloat16 h = __float2bfloat16(f);
    return (unsigned int)__builtin_bit_cast(unsigned short, h);
}
static __device__ __forceinline__ float bf2f_lo(unsigned int u) {
    return __builtin_bit_cast(float, (u & 0xffffu) << 16);
}
static __device__ __forceinline__ float bf2f_hi(unsigned int u) {
    return __builtin_bit_cast(float, u & 0xffff0000u);
}

// tableA layout: [16][257][512] bf16; row 256 of each p is ZERO (missing id).
#define TP_STRIDE (257 * 512)

// ---------------------------------------------------------------------------
// k_prep: blocks 0..511 cast up_w; 512..639 cast byte_emb; 640..655 zero the
// 16 pad rows of tableA.
// ---------------------------------------------------------------------------
__global__ __launch_bounds__(256) void k_prep(
    const float* __restrict__ up_w, const float* __restrict__ byte_emb,
    unsigned short* __restrict__ wb, unsigned short* __restrict__ bb,
    unsigned short* __restrict__ T)
{
    const int b = blockIdx.x;
    if (b < 640) {
        const float* src;
        unsigned short* dst;
        int idx;
        if (b < 512) { src = up_w;     dst = wb; idx = (b * 256 + threadIdx.x) * 4; }
        else         { src = byte_emb; dst = bb; idx = ((b - 512) * 256 + threadIdx.x) * 4; }
        const float4 v = *(const float4*)&src[idx];
        ushort4 o;
        o.x = (unsigned short)f2bfu(v.x); o.y = (unsigned short)f2bfu(v.y);
        o.z = (unsigned short)f2bfu(v.z); o.w = (unsigned short)f2bfu(v.w);
        *(ushort4*)&dst[idx] = o;
    } else {
        const int p = b - 640;
        if (threadIdx.x < 128) {
            ushort4 z; z.x = z.y = z.z = z.w = 0;
            *(ushort4*)&T[(size_t)p * TP_STRIDE + 256 * 512 + threadIdx.x * 4] = z;
        }
    }
}

// ---------------------------------------------------------------------------
// k1_t: tableA[p][m][j] = sum_i bb[m][i] * pos_emb[p][i][j]   (bf16 MFMA)
// K-step 64, double-buffered LDS transpose of pos_emb, 1 barrier/iter,
// next-step loads overlapped with MFMA (T14).
// Block 256 thr = 4 waves (2m x 2j); block tile 64m x 64j; grid (8,4,16).
// ---------------------------------------------------------------------------
__global__ __launch_bounds__(256) void k1_t(
    const unsigned short* __restrict__ A,   // bb [256][512] bf16
    const float* __restrict__ P,            // pos_emb [16][512][512] f32
    unsigned short* __restrict__ T)         // tableA [16][257][512] bf16
{
    const int p  = blockIdx.z;
    const int j0 = blockIdx.x * 64;
    const int m0 = blockIdx.y * 64;
    const float* __restrict__ Pp = P + (size_t)p * 512 * 512;
    unsigned short* __restrict__ Tp = T + (size_t)p * TP_STRIDE;

    __shared__ unsigned short Bs[2][64][72];   // [j][i], 144B rows

    const int tid  = threadIdx.x;
    const int w    = tid >> 6, lane = tid & 63;
    const int lr   = lane & 15, lg = lane >> 4, lk = lg * 8;
    const int wr   = w >> 1, wc = w & 1;
    const int jq   = tid & 15;              // j quad: j = 4*jq..+3
    const int ip   = tid >> 4;              // i pairs: {2ip,2ip+1}, {2ip+32,2ip+33}

    float4 v0, v1, v2, v3;
    #define LOADP(it) do {                                                    \
        const float* bp = Pp + (size_t)((it) * 64) * 512 + j0 + 4 * jq;       \
        v0 = *(const float4*)&bp[(size_t)(2 * ip)      * 512];                \
        v1 = *(const float4*)&bp[(size_t)(2 * ip + 1)  * 512];                \
        v2 = *(const float4*)&bp[(size_t)(2 * ip + 32) * 512];                \
        v3 = *(const float4*)&bp[(size_t)(2 * ip + 33) * 512];                \
    } while (0)
    #define WRITEB(buf) do {                                                  \
        *(unsigned int*)&Bs[buf][4 * jq + 0][2 * ip]        = f2bfu(v0.x) | (f2bfu(v1.x) << 16); \
        *(unsigned int*)&Bs[buf][4 * jq + 1][2 * ip]        = f2bfu(v0.y) | (f2bfu(v1.y) << 16); \
        *(unsigned int*)&Bs[buf][4 * jq + 2][2 * ip]        = f2bfu(v0.z) | (f2bfu(v1.z) << 16); \
        *(unsigned int*)&Bs[buf][4 * jq + 3][2 * ip]        = f2bfu(v0.w) | (f2bfu(v1.w) << 16); \
        *(unsigned int*)&Bs[buf][4 * jq + 0][2 * (ip + 16)] = f2bfu(v2.x) | (f2bfu(v3.x) << 16); \
        *(unsigned int*)&Bs[buf][4 * jq + 1][2 * (ip + 16)] = f2bfu(v2.y) | (f2bfu(v3.y) << 16); \
        *(unsigned int*)&Bs[buf][4 * jq + 2][2 * (ip + 16)] = f2bfu(v2.z) | (f2bfu(v3.z) << 16); \
        *(unsigned int*)&Bs[buf][4 * jq + 3][2 * (ip + 16)] = f2bfu(v2.w) | (f2bfu(v3.w) << 16); \
    } while (0)

    floatx4 acc[2][2] = {};

    LOADP(0);
    WRITEB(0);
    __syncthreads();

    for (int it = 0; it < 8; ++it) {
        if (it < 7) LOADP(it + 1);
        #pragma unroll
        for (int kf = 0; kf < 2; ++kf) {
            short8 a[2], bfr[2];
            #pragma unroll
            for (int mf = 0; mf < 2; ++mf)
                a[mf] = *(const short8*)&A[(size_t)(m0 + wr * 32 + mf * 16 + lr) * 512
                                           + it * 64 + kf * 32 + lk];
            #pragma unroll
            for (int nf = 0; nf < 2; ++nf)
                bfr[nf] = *(const short8*)&Bs[it & 1][wc * 32 + nf * 16 + lr][kf * 32 + lk];
            #pragma unroll
            for (int mf = 0; mf < 2; ++mf)
                #pragma unroll
                for (int nf = 0; nf < 2; ++nf)
                    acc[mf][nf] = __builtin_amdgcn_mfma_f32_16x16x32_bf16(
                        a[mf], bfr[nf], acc[mf][nf], 0, 0, 0);
        }
        if (it < 7) {
            WRITEB((it + 1) & 1);
            __syncthreads();
        }
    }

    #pragma unroll
    for (int nf = 0; nf < 2; ++nf)
        #pragma unroll
        for (int mf = 0; mf < 2; ++mf)
            #pragma unroll
            for (int q = 0; q < 4; ++q)
                Tp[(size_t)(m0 + wr * 32 + mf * 16 + lg * 4 + q) * 512
                   + j0 + wc * 32 + nf * 16 + lr]
                    = (unsigned short)f2bfu(acc[mf][nf][q]);
    #undef LOADP
    #undef WRITEB
}

// ---------------------------------------------------------------------------
// k_fused: gather + up-projection + LayerNorm.
// Block = 32 rows x 1024 cols, 1024 thr = 16 waves; wave w -> cols w*64..+63
// (wave tile 32x64: mf2 x nf4). K-step 64 (8 iters), dbuf A_lds, 1 barrier/
// iter; gather loads for step it+1 issued before step it's MFMAs (T14).
// Missing ids map to tableA's zero row (no mask math).
// ---------------------------------------------------------------------------
__global__ __launch_bounds__(1024) void k_fused(
    const int* __restrict__ ids,            // [rows][16]
    const unsigned short* __restrict__ T,   // tableA [16][257][512] bf16
    const unsigned short* __restrict__ Bw,  // up_w [1024][512] bf16
    const float* __restrict__ up_b,
    const float* __restrict__ gamma,
    const float* __restrict__ beta,
    float* __restrict__ out)                // [rows][1024] f32
{
    const int r0   = blockIdx.x * 32;
    const int tid  = threadIdx.x;
    const int w    = tid >> 6, lane = tid & 63;
    const int lr   = lane & 15, lg = lane >> 4, lk = lg * 8;
    const int colb = w * 64;

    __shared__ unsigned short A_lds[2][32][72];   // [row][k], 144B rows
    __shared__ int   ids_s[512];
    __shared__ float redS[32][17], redQ[32][17];

    if (tid < 512) ids_s[tid] = ids[r0 * 16 + tid];
    __syncthreads();

    const int grow = tid >> 5, gc = tid & 31;     // gather: row 0..31, k-pair 0..31
    unsigned int goff[16];
    #pragma unroll
    for (int p = 0; p < 16; ++p) {
        const int id = ids_s[grow * 16 + p];
        goff[p] = (unsigned int)((p * 257 + (id < 0 ? 256 : id)) * 512 + 2 * gc);
    }

    floatx4 acc[2][4] = {};
    unsigned int u[16];

    #define GLOAD(it) do {                                                    \
        _Pragma("unroll")                                                     \
        for (int p = 0; p < 16; ++p)                                          \
            u[p] = *(const unsigned int*)&T[goff[p] + (it) * 64];             \
    } while (0)
    #define REDWRITE(buf) do {                                                \
        float f0 = 0.0f, f1 = 0.0f;                                           \
        _Pragma("unroll")                                                     \
        for (int p = 0; p < 16; ++p) { f0 += bf2f_lo(u[p]); f1 += bf2f_hi(u[p]); } \
        *(unsigned int*)&A_lds[buf][grow][2 * gc] = f2bfu(f0) | (f2bfu(f1) << 16); \
    } while (0)

    GLOAD(0);
    REDWRITE(0);
    __syncthreads();

    for (int it = 0; it < 8; ++it) {
        if (it < 7) GLOAD(it + 1);
        #pragma unroll
        for (int kf = 0; kf < 2; ++kf) {
            short8 a[2], bfr[4];
            #pragma unroll
            for (int mf = 0; mf < 2; ++mf)
                a[mf] = *(const short8*)&A_lds[it & 1][mf * 16 + lr][kf * 32 + lk];
            #pragma unroll
            for (int nf = 0; nf < 4; ++nf)
                bfr[nf] = *(const short8*)&Bw[(size_t)(colb + nf * 16 + lr) * 512
                                              + it * 64 + kf * 32 + lk];
            #pragma unroll
            for (int mf = 0; mf < 2; ++mf)
                #pragma unroll
                for (int nf = 0; nf < 4; ++nf)
                    acc[mf][nf] = __builtin_amdgcn_mfma_f32_16x16x32_bf16(
                        a[mf], bfr[nf], acc[mf][nf], 0, 0, 0);
        }
        if (it < 7) {
            REDWRITE((it + 1) & 1);
            __syncthreads();
        }
    }
    #undef GLOAD
    #undef REDWRITE

    // bias
    #pragma unroll
    for (int nf = 0; nf < 4; ++nf) {
        const float bias = up_b[colb + nf * 16 + lr];
        #pragma unroll
        for (int mf = 0; mf < 2; ++mf)
            #pragma unroll
            for (int q = 0; q < 4; ++q)
                acc[mf][nf][q] += bias;
    }

    // per-lane partials over this wave's 64 cols (reduce across the 16-lane group)
    float s[2][4], ss[2][4];
    #pragma unroll
    for (int mf = 0; mf < 2; ++mf)
        #pragma unroll
        for (int q = 0; q < 4; ++q) {
            float t1 = 0.0f, t2 = 0.0f;
            #pragma unroll
            for (int nf = 0; nf < 4; ++nf) {
                const float v = acc[mf][nf][q];
                t1 += v; t2 += v * v;
            }
            #pragma unroll
            for (int off = 1; off < 16; off <<= 1) {
                t1 += __shfl_xor(t1, off, 16);
                t2 += __shfl_xor(t2, off, 16);
            }
            s[mf][q] = t1; ss[mf][q] = t2;
        }

    if (lr == 0) {
        #pragma unroll
        for (int mf = 0; mf < 2; ++mf)
            #pragma unroll
            for (int q = 0; q < 4; ++q) {
                const int row = mf * 16 + lg * 4 + q;
                redS[row][w] = s[mf][q];
                redQ[row][w] = ss[mf][q];
            }
    }
    __syncthreads();

    float mu[2][4], rs[2][4];
    #pragma unroll
    for (int mf = 0; mf < 2; ++mf)
        #pragma unroll
        for (int q = 0; q < 4; ++q) {
            const int row = mf * 16 + lg * 4 + q;
            float S = 0.0f, SS = 0.0f;
            #pragma unroll
            for (int ww = 0; ww < 16; ++ww) { S += redS[row][ww]; SS += redQ[row][ww]; }
            const float m = S * (1.0f / 1024.0f);
            const float var = SS * (1.0f / 1024.0f) - m * m;
            mu[mf][q] = m;
            rs[mf][q] = rsqrtf(var + LN_EPS);
        }

    #pragma unroll
    for (int nf = 0; nf < 4; ++nf) {
        const int col = colb + nf * 16 + lr;
        const float g  = gamma[col];
        const float be = beta[col];
        #pragma unroll
        for (int mf = 0; mf < 2; ++mf)
            #pragma unroll
            for (int q = 0; q < 4; ++q) {
                const int row = mf * 16 + lg * 4 + q;
                out[(size_t)(r0 + row) * 1024 + col]
                    = (acc[mf][nf][q] - mu[mf][q]) * rs[mf][q] * g + be;
            }
    }
}

extern "C" void kernel_launch(void* const* d_in, const int* in_sizes, int n_in,
                              void* d_out, int out_size, void* d_ws, size_t ws_size,
                              hipStream_t stream) {
    const int*   ids      = (const int*)d_in[0];
    const float* byte_emb = (const float*)d_in[1];
    const float* pos_emb  = (const float*)d_in[2];
    const float* up_w     = (const float*)d_in[3];
    const float* up_b     = (const float*)d_in[4];
    const float* gamma    = (const float*)d_in[5];
    const float* beta     = (const float*)d_in[6];
    float* out = (float*)d_out;

    // ws: wb [1024][512] 1MB | bb [256][512] 0.25MB | tableA [16][257][512] ~4.2MB
    unsigned short* wb     = (unsigned short*)d_ws;
    unsigned short* bb     = wb + (size_t)1024 * 512;
    unsigned short* tableA = bb + (size_t)256 * 512;

    const int rows = in_sizes[0] / 16;   // 8192

    k_prep<<<656, 256, 0, stream>>>(up_w, byte_emb, wb, bb, tableA);

    dim3 g1(8, 4, 16);
    k1_t<<<g1, 256, 0, stream>>>(bb, pos_emb, tableA);

    k_fused<<<rows / 32, 1024, 0, stream>>>(ids, tableA, wb, up_b, gamma, beta, out);
}